// Round 4
// baseline (448.158 us; speedup 1.0000x reference)
//
#include <hip/hip_runtime.h>
#include <hip/hip_bf16.h>
#include <stdint.h>

// ---------- types ----------
typedef __attribute__((ext_vector_type(8))) short     bf16x8;  // MFMA A/B frag (4 VGPR)
typedef __attribute__((ext_vector_type(4))) float     f32x4;   // MFMA C/D frag

__device__ __forceinline__ unsigned short f2bf(float f) {
  unsigned int u = __float_as_uint(f);
  u += 0x7FFFu + ((u >> 16) & 1u);   // round-to-nearest-even
  return (unsigned short)(u >> 16);
}

__device__ __forceinline__ void async_cp16(const void* g, void* l) {
  __builtin_amdgcn_global_load_lds((const __attribute__((address_space(1))) void*)g,
                                   (__attribute__((address_space(3))) void*)l,
                                   16, 0, 0);
}

// ---------- fp32 -> bf16 conversion (memory-bound, vectorized) ----------
__global__ __launch_bounds__(256) void cvt_f32_to_bf16(const float* __restrict__ in,
                                                       unsigned short* __restrict__ out,
                                                       int n4) {
  int i = blockIdx.x * blockDim.x + threadIdx.x;
  const int stride = gridDim.x * blockDim.x;
  for (; i < n4; i += stride) {
    const float4 v = ((const float4*)in)[i];
    ushort4 o;
    o.x = f2bf(v.x); o.y = f2bf(v.y); o.z = f2bf(v.z); o.w = f2bf(v.w);
    ((ushort4*)out)[i] = o;
  }
}

// ---------- fp32 -> bf16 with gate/up row interleave ----------
// out row r: g = r>>5, w = r&31; src = g*16 + (w&15) + (w>=16 ? 2048 : 0)
// -> each 32-row group = 16 gate rows + 16 up rows of the same e-block.
__global__ __launch_bounds__(256) void cvt_wug_perm(const float* __restrict__ in,
                                                    unsigned short* __restrict__ out,
                                                    int n4) {            // 4096*1792
  int i = blockIdx.x * blockDim.x + threadIdx.x;
  const int stride = gridDim.x * blockDim.x;
  for (; i < n4; i += stride) {
    const int r = i / 1792, c = i - r * 1792;
    const int g = r >> 5, w = r & 31;
    const int src = g * 16 + (w & 15) + ((w & 16) ? 2048 : 0);
    const float4 v = ((const float4*)in)[(size_t)src * 1792 + c];
    ushort4 o;
    o.x = f2bf(v.x); o.y = f2bf(v.y); o.z = f2bf(v.z); o.w = f2bf(v.w);
    ((ushort4*)out)[(size_t)r * 1792 + c] = o;
  }
}

// ---------- 256x128 deep-pipelined NT bf16 GEMM, 2 blocks/CU ----------
// C[m,n] = sum_k A[m,k]*B[n,k].  256 threads = 4 waves (2Mx2N), wave = 128x64 out.
// LDS ring-3 at kstep (32-elem) granularity: slot = 16KB A + 8KB B = 72KiB total
// -> 2 blocks/CU co-resident; their independent barrier groups decorrelate the
// ds_read and MFMA phases (the round-3 stall was 1-block/CU phase alignment).
// Per kstep: read frags, stage kstep h+2 (6 gload_lds), 32 MFMA, vmcnt(6)+barrier.
// vmcnt(6) drains only kstep h+1's loads; h+2's stay in flight (never 0).
// LDS line L (128B) = rows 2L,2L+1; 16B-slot swizzle p = q ^ (L&7); staging
// pre-swizzles the per-lane GLOBAL source, LDS dest stays linear (m173).
// FUSE_SWIGLU: B rows pre-permuted so frag n in {0,2}=gate, {1,3}=up of the
// same e-cols -> h = silu(g)*u in-lane, write [M, N/2] bf16.
template <int K, int N, bool FUSE_SWIGLU>
__global__ __launch_bounds__(256, 2) void gemm_nt(const unsigned short* __restrict__ A,
                                                  const unsigned short* __restrict__ B,
                                                  void* __restrict__ Cv) {
  extern __shared__ char sm[];   // 73728 B: 3 slots x (16KB A + 8KB B)
  constexpr int nbx = N / 128;
  constexpr int nwg = (4096 / 256) * nbx;
  constexpr size_t K2 = (size_t)K * 2;

  // T1: bijective XCD swizzle (nwg % 8 == 0 for both GEMMs)
  const int bid = blockIdx.x;
  constexpr int q8 = nwg / 8;
  const int swz = (bid & 7) * q8 + (bid >> 3);
  const int bx = swz % nbx, by = swz / nbx;
  const int row0 = by * 256, col0 = bx * 128;

  const int tid = threadIdx.x, wave = tid >> 6, lane = tid & 63;
  const int wr = wave >> 1, wc = wave & 1;       // wave 2x2 grid
  const int fr = lane & 15, fg = lane >> 4;      // fragment row / k-group

  // ---- staging addresses (pre-swizzled global source, linear LDS dest) ----
  const int l3 = lane >> 3;                 // 0..7
  const int q  = (lane & 7) ^ l3;           // 0..7 involution
  const int qr = q >> 2;                    // row parity
  const int qc = (q & 3) * 16;              // byte offset within kstep's 64B row
  const char* gA[4]; const char* gB[2];
#pragma unroll
  for (int i = 0; i < 4; ++i) {
    const int L = wave * 32 + i * 8 + l3;   // A line 0..127 (256 rows)
    gA[i] = (const char*)A + (size_t)(row0 + 2 * L + qr) * K2 + qc;
  }
#pragma unroll
  for (int i = 0; i < 2; ++i) {
    const int L = wave * 16 + i * 8 + l3;   // B line 0..63 (128 rows)
    gB[i] = (const char*)B + (size_t)(col0 + 2 * L + qr) * K2 + qc;
  }

  // ---- fragment read offsets (swizzled) ----
  const int rbA = wr * 128 + fr;
  const int offA0 = (rbA >> 1) * 128 + (((((rbA & 1) << 2) | fg) ^ ((rbA >> 1) & 7)) << 4);
  const int rbB = wc * 64 + fr;
  const int offB0 = (rbB >> 1) * 128 + (((((rbB & 1) << 2) | fg) ^ ((rbB >> 1) & 7)) << 4);

  f32x4 acc[8][4];
#pragma unroll
  for (int m = 0; m < 8; ++m)
#pragma unroll
    for (int n = 0; n < 4; ++n) acc[m][n] = (f32x4){0.f, 0.f, 0.f, 0.f};

  constexpr int nh = K / 32;    // ksteps

#define STAGE(hh, slot) do {                                        \
    char* da = sm + (slot) * 24576 + wave * 4096;                   \
    char* db = sm + (slot) * 24576 + 16384 + wave * 2048;           \
    async_cp16(gA[0] + (size_t)(hh) * 64, da);                      \
    async_cp16(gA[1] + (size_t)(hh) * 64, da + 1024);               \
    async_cp16(gA[2] + (size_t)(hh) * 64, da + 2048);               \
    async_cp16(gA[3] + (size_t)(hh) * 64, da + 3072);               \
    async_cp16(gB[0] + (size_t)(hh) * 64, db);                      \
    async_cp16(gB[1] + (size_t)(hh) * 64, db + 1024);               \
  } while (0)

  // prologue: stage ksteps 0,1 (12 loads); drain kstep 0's -> slot 0 ready
  STAGE(0, 0);
  STAGE(1, 1);
  asm volatile("s_waitcnt vmcnt(6)" ::: "memory");
  __builtin_amdgcn_s_barrier();

  for (int h = 0; h < nh; ++h) {
    const int slot  = h % 3;
    const char* aBase = sm + slot * 24576;
    const char* bBase = sm + slot * 24576 + 16384;
    const int hs    = (h + 2 < nh) ? h + 2 : nh - 1;  // clamp keeps vmcnt discipline
    const int sslot = (h + 2) % 3;                    // last read in kstep h-1

    bf16x8 af[4], bfr[4];
#pragma unroll
    for (int n = 0; n < 4; ++n) bfr[n] = *(const bf16x8*)(bBase + offB0 + n * 1024);
#pragma unroll
    for (int m = 0; m < 4; ++m) af[m] = *(const bf16x8*)(aBase + offA0 + m * 1024);
    STAGE(hs, sslot);   // issue early: a full kstep of latency headroom
    __builtin_amdgcn_s_setprio(1);
#pragma unroll
    for (int m = 0; m < 4; ++m)
#pragma unroll
      for (int n = 0; n < 4; ++n)
        acc[m][n] = __builtin_amdgcn_mfma_f32_16x16x32_bf16(af[m], bfr[n], acc[m][n], 0, 0, 0);
    __builtin_amdgcn_s_setprio(0);

#pragma unroll
    for (int m = 0; m < 4; ++m) af[m] = *(const bf16x8*)(aBase + offA0 + (m + 4) * 1024);
    __builtin_amdgcn_s_setprio(1);
#pragma unroll
    for (int m = 0; m < 4; ++m)
#pragma unroll
      for (int n = 0; n < 4; ++n)
        acc[m + 4][n] = __builtin_amdgcn_mfma_f32_16x16x32_bf16(af[m], bfr[n], acc[m + 4][n], 0, 0, 0);
    __builtin_amdgcn_s_setprio(0);

    // single sync point: kstep h+1's loads drained (12 -> 6 outstanding)
    asm volatile("s_waitcnt vmcnt(6)" ::: "memory");
    __builtin_amdgcn_s_barrier();
  }
#undef STAGE

  // ---- epilogue: C/D layout col = lane&15, row = (lane>>4)*4 + j (m89-verified) ----
  const int rowb = row0 + wr * 128 + fg * 4;
  if (FUSE_SWIGLU) {
    // frag n in {0,2}: gate; {1,3}: up, same e-cols (pre-permuted B)
    unsigned short* Hp = (unsigned short*)Cv;
    const int ecb = ((col0 + wc * 64) >> 1) + fr;
#pragma unroll
    for (int m = 0; m < 8; ++m)
#pragma unroll
      for (int p = 0; p < 2; ++p)
#pragma unroll
        for (int j = 0; j < 4; ++j) {
          const float gv = acc[m][2 * p][j];
          const float uv = acc[m][2 * p + 1][j];
          const float s  = gv / (1.0f + __expf(-gv));
          Hp[(size_t)(rowb + m * 16 + j) * (N / 2) + (ecb + p * 16)] = f2bf(s * uv);
        }
  } else {
    float* Cp = (float*)Cv;
    const int colb = col0 + wc * 64 + fr;
#pragma unroll
    for (int m = 0; m < 8; ++m)
#pragma unroll
      for (int n = 0; n < 4; ++n)
#pragma unroll
        for (int j = 0; j < 4; ++j)
          Cp[(size_t)(rowb + m * 16 + j) * N + (colb + n * 16)] = acc[m][n][j];
  }
}

// ---------- launch ----------
extern "C" void kernel_launch(void* const* d_in, const int* in_sizes, int n_in,
                              void* d_out, int out_size, void* d_ws, size_t ws_size,
                              hipStream_t stream) {
  const int M = 4096, K = 7168, E = 2048;

  const float* x   = (const float*)d_in[0];  // [M,K]
  const float* wug = (const float*)d_in[1];  // [2E,K]
  const float* wd  = (const float*)d_in[2];  // [K,E]
  float* out = (float*)d_out;                // [M,K]

  // workspace layout (bytes)
  char* ws = (char*)d_ws;
  unsigned short* xb  = (unsigned short*)(ws);               //  58,720,256
  unsigned short* wub = (unsigned short*)(ws + 58720256);    //  58,720,256 (permuted)
  unsigned short* wdb = (unsigned short*)(ws + 117440512);   //  29,360,128
  unsigned short* h   = (unsigned short*)(ws + 146800640);   //  16,777,216
  if (ws_size < 163577856) return;                           // need ~156 MiB

  // allow 72 KiB dynamic LDS (host-side calls, safe under graph capture)
  hipFuncSetAttribute((const void*)gemm_nt<7168, 4096, true>,
                      hipFuncAttributeMaxDynamicSharedMemorySize, 73728);
  hipFuncSetAttribute((const void*)gemm_nt<2048, 7168, false>,
                      hipFuncAttributeMaxDynamicSharedMemorySize, 73728);

  // 1) cast inputs to bf16 (wug with gate/up interleave permutation)
  cvt_f32_to_bf16<<<2048, 256, 0, stream>>>(x,   xb,  M * K / 4);
  cvt_wug_perm  <<<2048, 256, 0, stream>>>(wug, wub, 2 * E * K / 4);
  cvt_f32_to_bf16<<<1024, 256, 0, stream>>>(wd,  wdb, K * E / 4);

  // 2) h = swiglu(x @ w_up_gate^T) fused   [4096, 2048] bf16  (16x32 = 512 blocks)
  gemm_nt<7168, 4096, true><<<512, 256, 73728, stream>>>(xb, wub, h);

  // 3) out = h @ w_down^T     [4096, 7168] fp32  (16x56 = 896 blocks)
  gemm_nt<2048, 7168, false><<<896, 256, 73728, stream>>>(h, wdb, out);
}

// Round 5
// 424.881 us; speedup vs baseline: 1.0548x; 1.0548x over previous
//
#include <hip/hip_runtime.h>
#include <hip/hip_bf16.h>
#include <stdint.h>

// ---------- types ----------
typedef __attribute__((ext_vector_type(8))) short     bf16x8;  // MFMA A/B frag (4 VGPR)
typedef __attribute__((ext_vector_type(4))) float     f32x4;   // MFMA C/D frag

__device__ __forceinline__ unsigned short f2bf(float f) {
  unsigned int u = __float_as_uint(f);
  u += 0x7FFFu + ((u >> 16) & 1u);   // round-to-nearest-even
  return (unsigned short)(u >> 16);
}

__device__ __forceinline__ void async_cp16(const void* g, void* l) {
  __builtin_amdgcn_global_load_lds((const __attribute__((address_space(1))) void*)g,
                                   (__attribute__((address_space(3))) void*)l,
                                   16, 0, 0);
}

// ---------- fp32 -> bf16 conversion (memory-bound, vectorized) ----------
__global__ __launch_bounds__(256) void cvt_f32_to_bf16(const float* __restrict__ in,
                                                       unsigned short* __restrict__ out,
                                                       int n4) {
  int i = blockIdx.x * blockDim.x + threadIdx.x;
  const int stride = gridDim.x * blockDim.x;
  for (; i < n4; i += stride) {
    const float4 v = ((const float4*)in)[i];
    ushort4 o;
    o.x = f2bf(v.x); o.y = f2bf(v.y); o.z = f2bf(v.z); o.w = f2bf(v.w);
    ((ushort4*)out)[i] = o;
  }
}

// ---------- fp32 -> bf16 with gate/up row interleave ----------
// out row r: g = r>>5, w = r&31; src = g*16 + (w&15) + (w>=16 ? 2048 : 0)
// -> each 32-row group = 16 gate rows + 16 up rows of the same e-block.
__global__ __launch_bounds__(256) void cvt_wug_perm(const float* __restrict__ in,
                                                    unsigned short* __restrict__ out,
                                                    int n4) {            // 4096*1792
  int i = blockIdx.x * blockDim.x + threadIdx.x;
  const int stride = gridDim.x * blockDim.x;
  for (; i < n4; i += stride) {
    const int r = i / 1792, c = i - r * 1792;
    const int g = r >> 5, w = r & 31;
    const int src = g * 16 + (w & 15) + ((w & 16) ? 2048 : 0);
    const float4 v = ((const float4*)in)[(size_t)src * 1792 + c];
    ushort4 o;
    o.x = f2bf(v.x); o.y = f2bf(v.y); o.z = f2bf(v.z); o.w = f2bf(v.w);
    ((ushort4*)out)[(size_t)r * 1792 + c] = o;
  }
}

// ---------- 256x256 4-phase NT bf16 GEMM (m201-template port) ----------
// C[m,n] = sum_k A[m,k]*B[n,k].  512 thr = 8 waves (2Mx4N), wave-tile 128x64.
// BK=64, double-buffered LDS: buf = [A kg0 16K][A kg1 16K][B kg0 16K][B kg1 16K]
// = 64 KiB, x2 = 128 KiB. Per K-tile: 4 phases, one C-quadrant (mh,nh) each,
// order (0,0),(0,1),(1,1),(1,0): A-frags read twice, both B n-halves stay live.
// Phase = {ds_reads for this quadrant | 4 staging gloads (ph0:A, ph1:B)} ->
// barrier -> setprio(1) 16 MFMA setprio(0) -> barrier. The 16 MFMAs drain
// ~620 cyc/SIMD while the next phase's reads+barrier issue underneath.
// vmcnt(0) in ph3: youngest staging load is >=2 phases (~1200 cyc) old.
// Swizzle (proven 0-conflict): line L (128B) = rows 2L,2L+1 per kg-subtile;
// 16B-slot p holds logical q = p ^ (L&7); staging pre-swizzles the GLOBAL
// source per-lane, LDS dest stays linear (m173).
// FUSE_SWIGLU: B rows pre-permuted so acc n in {0,2}=gate, {1,3}=up of the
// same e-cols -> h = silu(g)*u in-lane, write [M, N/2] bf16.
template <int K, int N, bool FUSE_SWIGLU>
__global__ __launch_bounds__(512, 2) void gemm_nt(const unsigned short* __restrict__ A,
                                                  const unsigned short* __restrict__ B,
                                                  void* __restrict__ Cv) {
  extern __shared__ char sm[];   // 131072 B
  constexpr int nbx = N / 256;
  constexpr int nwg = (4096 / 256) * nbx;
  constexpr size_t K2 = (size_t)K * 2;
  constexpr int nt = K / 64;     // K-tiles

  // T1: bijective XCD swizzle (nwg % 8 == 0 for both GEMMs)
  const int bid = blockIdx.x;
  constexpr int q8 = nwg / 8;
  const int swz = (bid & 7) * q8 + (bid >> 3);
  const int bx = swz % nbx, by = swz / nbx;
  const int row0 = by * 256, col0 = bx * 256;

  const int tid = threadIdx.x, wave = tid >> 6, lane = tid & 63;
  const int wr = wave >> 2, wc = wave & 3;       // wave 2x4 grid
  const int fr = lane & 15, fg = lane >> 4;      // fragment row / k-group

  // ---- staging setup: 4 A-gloads + 4 B-gloads per wave per K-tile ----
  const int pp = lane & 7, l3 = lane >> 3;
  const char* srcA[4]; const char* srcB[4]; int dstA[4]; int dstB[4];
#pragma unroll
  for (int i = 0; i < 4; ++i) {
    const int j  = wave * 4 + i;        // 0..31 block-wide per matrix
    const int kg = j >> 4;              // k-subgroup 0/1 (32 elems each)
    const int lb = j & 15;              // line-block (8 lines = 1 KB)
    const int L  = lb * 8 + l3;         // LDS line 0..127
    const int q  = pp ^ (L & 7);        // pre-swizzled logical slot
    const int qr = q >> 2;              // row parity
    const int qc = (q & 3) * 16;        // byte offset within row's 64B kg-span
    srcA[i] = (const char*)A + (size_t)(row0 + 2 * L + qr) * K2 + kg * 64 + qc;
    srcB[i] = (const char*)B + (size_t)(col0 + 2 * L + qr) * K2 + kg * 64 + qc;
    dstA[i] = kg * 16384 + lb * 1024 + lane * 16;
    dstB[i] = 32768 + dstA[i];
  }

  // ---- fragment read offsets (swizzled, within a 16K kg-subtile) ----
  const int rbA = wr * 128 + fr;
  const int offA0 = (rbA >> 1) * 128 + (((((rbA & 1) << 2) | fg) ^ ((rbA >> 1) & 7)) << 4);
  const int rbB = wc * 64 + fr;
  const int offB0 = (rbB >> 1) * 128 + (((((rbB & 1) << 2) | fg) ^ ((rbB >> 1) & 7)) << 4);

  f32x4 acc[8][4];
#pragma unroll
  for (int m = 0; m < 8; ++m)
#pragma unroll
    for (int n = 0; n < 4; ++n) acc[m][n] = (f32x4){0.f, 0.f, 0.f, 0.f};

#define STAGE_A(tt, bufb) do {                                              \
    _Pragma("unroll")                                                       \
    for (int i_ = 0; i_ < 4; ++i_)                                          \
      async_cp16(srcA[i_] + (size_t)(tt) * 128, (bufb) + dstA[i_]);         \
  } while (0)
#define STAGE_B(tt, bufb) do {                                              \
    _Pragma("unroll")                                                       \
    for (int i_ = 0; i_ < 4; ++i_)                                          \
      async_cp16(srcB[i_] + (size_t)(tt) * 128, (bufb) + dstB[i_]);         \
  } while (0)

  // prologue: stage tile 0 into buf0, drain, sync
  STAGE_A(0, sm); STAGE_B(0, sm);
  asm volatile("s_waitcnt vmcnt(0)" ::: "memory");
  __builtin_amdgcn_s_barrier();

  bf16x8 af[2][4], bfA[2][2], bfB[2][2];

  for (int t = 0; t < nt; ++t) {
    char* cur = sm + (t & 1) * 65536;
    char* nxt = sm + ((t + 1) & 1) * 65536;
    const bool do_stage = (t + 1 < nt);

    // ---- phase 0: quadrant (mh=0, nh=0) ----
#pragma unroll
    for (int kg = 0; kg < 2; ++kg) {
#pragma unroll
      for (int mt = 0; mt < 4; ++mt)
        af[kg][mt] = *(const bf16x8*)(cur + kg * 16384 + offA0 + mt * 1024);
#pragma unroll
      for (int nn = 0; nn < 2; ++nn)
        bfA[kg][nn] = *(const bf16x8*)(cur + 32768 + kg * 16384 + offB0 + nn * 1024);
    }
    if (do_stage) STAGE_A(t + 1, nxt);
    __builtin_amdgcn_s_barrier();
    __builtin_amdgcn_s_setprio(1);
#pragma unroll
    for (int mt = 0; mt < 4; ++mt)
#pragma unroll
      for (int nn = 0; nn < 2; ++nn)
#pragma unroll
        for (int kg = 0; kg < 2; ++kg)
          acc[mt][nn] = __builtin_amdgcn_mfma_f32_16x16x32_bf16(af[kg][mt], bfA[kg][nn], acc[mt][nn], 0, 0, 0);
    __builtin_amdgcn_s_setprio(0);
    __builtin_amdgcn_s_barrier();

    // ---- phase 1: quadrant (0, 1) ----
#pragma unroll
    for (int kg = 0; kg < 2; ++kg)
#pragma unroll
      for (int nn = 0; nn < 2; ++nn)
        bfB[kg][nn] = *(const bf16x8*)(cur + 32768 + kg * 16384 + offB0 + (2 + nn) * 1024);
    if (do_stage) STAGE_B(t + 1, nxt);
    __builtin_amdgcn_s_barrier();
    __builtin_amdgcn_s_setprio(1);
#pragma unroll
    for (int mt = 0; mt < 4; ++mt)
#pragma unroll
      for (int nn = 0; nn < 2; ++nn)
#pragma unroll
        for (int kg = 0; kg < 2; ++kg)
          acc[mt][2 + nn] = __builtin_amdgcn_mfma_f32_16x16x32_bf16(af[kg][mt], bfB[kg][nn], acc[mt][2 + nn], 0, 0, 0);
    __builtin_amdgcn_s_setprio(0);
    __builtin_amdgcn_s_barrier();

    // ---- phase 2: quadrant (1, 1) ----
#pragma unroll
    for (int kg = 0; kg < 2; ++kg)
#pragma unroll
      for (int mt = 0; mt < 4; ++mt)
        af[kg][mt] = *(const bf16x8*)(cur + kg * 16384 + offA0 + (4 + mt) * 1024);
    __builtin_amdgcn_s_barrier();
    __builtin_amdgcn_s_setprio(1);
#pragma unroll
    for (int mt = 0; mt < 4; ++mt)
#pragma unroll
      for (int nn = 0; nn < 2; ++nn)
#pragma unroll
        for (int kg = 0; kg < 2; ++kg)
          acc[4 + mt][2 + nn] = __builtin_amdgcn_mfma_f32_16x16x32_bf16(af[kg][mt], bfB[kg][nn], acc[4 + mt][2 + nn], 0, 0, 0);
    __builtin_amdgcn_s_setprio(0);
    __builtin_amdgcn_s_barrier();

    // ---- phase 3: quadrant (1, 0) — no reads; drain staging under MFMA ----
    __builtin_amdgcn_s_setprio(1);
#pragma unroll
    for (int mt = 0; mt < 4; ++mt)
#pragma unroll
      for (int nn = 0; nn < 2; ++nn)
#pragma unroll
        for (int kg = 0; kg < 2; ++kg)
          acc[4 + mt][nn] = __builtin_amdgcn_mfma_f32_16x16x32_bf16(af[kg][mt], bfA[kg][nn], acc[4 + mt][nn], 0, 0, 0);
    __builtin_amdgcn_s_setprio(0);
    asm volatile("s_waitcnt vmcnt(0)" ::: "memory");   // youngest load ~2 phases old
    __builtin_amdgcn_s_barrier();
  }
#undef STAGE_A
#undef STAGE_B

  // ---- epilogue: C/D layout col = lane&15, row = (lane>>4)*4 + j (m89-verified) ----
  const int rowb = row0 + wr * 128 + fg * 4;
  if (FUSE_SWIGLU) {
    // acc n in {0,2}: gate; {1,3}: up, same e-cols (pre-permuted B)
    unsigned short* Hp = (unsigned short*)Cv;
    const int ecb = ((col0 + wc * 64) >> 1) + fr;
#pragma unroll
    for (int m = 0; m < 8; ++m)
#pragma unroll
      for (int p = 0; p < 2; ++p)
#pragma unroll
        for (int j = 0; j < 4; ++j) {
          const float gv = acc[m][2 * p][j];
          const float uv = acc[m][2 * p + 1][j];
          const float s  = gv / (1.0f + __expf(-gv));
          Hp[(size_t)(rowb + m * 16 + j) * (N / 2) + (ecb + p * 16)] = f2bf(s * uv);
        }
  } else {
    float* Cp = (float*)Cv;
    const int colb = col0 + wc * 64 + fr;
#pragma unroll
    for (int m = 0; m < 8; ++m)
#pragma unroll
      for (int n = 0; n < 4; ++n)
#pragma unroll
        for (int j = 0; j < 4; ++j)
          Cp[(size_t)(rowb + m * 16 + j) * N + (colb + n * 16)] = acc[m][n][j];
  }
}

// ---------- launch ----------
extern "C" void kernel_launch(void* const* d_in, const int* in_sizes, int n_in,
                              void* d_out, int out_size, void* d_ws, size_t ws_size,
                              hipStream_t stream) {
  const int M = 4096, K = 7168, E = 2048;

  const float* x   = (const float*)d_in[0];  // [M,K]
  const float* wug = (const float*)d_in[1];  // [2E,K]
  const float* wd  = (const float*)d_in[2];  // [K,E]
  float* out = (float*)d_out;                // [M,K]

  // workspace layout (bytes)
  char* ws = (char*)d_ws;
  unsigned short* xb  = (unsigned short*)(ws);               //  58,720,256
  unsigned short* wub = (unsigned short*)(ws + 58720256);    //  58,720,256 (permuted)
  unsigned short* wdb = (unsigned short*)(ws + 117440512);   //  29,360,128
  unsigned short* h   = (unsigned short*)(ws + 146800640);   //  16,777,216
  if (ws_size < 163577856) return;                           // need ~156 MiB

  // allow 128 KiB dynamic LDS (host-side calls, safe under graph capture)
  hipFuncSetAttribute((const void*)gemm_nt<7168, 4096, true>,
                      hipFuncAttributeMaxDynamicSharedMemorySize, 131072);
  hipFuncSetAttribute((const void*)gemm_nt<2048, 7168, false>,
                      hipFuncAttributeMaxDynamicSharedMemorySize, 131072);

  // 1) cast inputs to bf16 (wug with gate/up interleave permutation)
  cvt_f32_to_bf16<<<2048, 256, 0, stream>>>(x,   xb,  M * K / 4);
  cvt_wug_perm  <<<2048, 256, 0, stream>>>(wug, wub, 2 * E * K / 4);
  cvt_f32_to_bf16<<<1024, 256, 0, stream>>>(wd,  wdb, K * E / 4);

  // 2) h = swiglu(x @ w_up_gate^T) fused   [4096, 2048] bf16  (16x16 = 256 blocks)
  gemm_nt<7168, 4096, true><<<256, 512, 131072, stream>>>(xb, wub, h);

  // 3) out = h @ w_down^T     [4096, 7168] fp32  (16x28 = 448 blocks)
  gemm_nt<2048, 7168, false><<<448, 512, 131072, stream>>>(h, wdb, out);
}